// Round 10
// baseline (254.177 us; speedup 1.0000x reference)
//
#include <hip/hip_runtime.h>

#define DIM 512
#define B_  64
#define L_  2048

typedef unsigned short u16;
typedef float f32x4 __attribute__((ext_vector_type(4)));
typedef short s16x8 __attribute__((ext_vector_type(8)));
typedef short s16x4 __attribute__((ext_vector_type(4)));

__device__ __forceinline__ u16 f2bf(float f) {
  union { float f; unsigned u; } x{f};
  unsigned r = x.u + 0x7FFFu + ((x.u >> 16) & 1u);
  return (u16)(r >> 16);
}

__device__ __forceinline__ float tanh_fast(float x) {
  float e2 = __expf(2.0f * x);
  return 1.0f - 2.0f / (e2 + 1.0f);
}

// ---------- prep: q = query @ Wq^T + bq ; Wr -> bf16 transposed [t][o][32k] ----------
__global__ __launch_bounds__(256) void prep_kernel(
    const float* __restrict__ query, const float* __restrict__ Wq,
    const float* __restrict__ bq, const float* __restrict__ Wr,
    float* __restrict__ q_out, u16* __restrict__ Wrbt) {
  const int blk = blockIdx.x;
  const int tid = threadIdx.x;
  if (blk < 64) {
    __shared__ float qs[DIM];
    for (int i = tid; i < DIM; i += 256) qs[i] = query[blk * DIM + i];
    __syncthreads();
    for (int o = tid; o < DIM; o += 256) {
      const float* w = Wq + o * DIM;
      float acc = 0.f;
      for (int k = 0; k < DIM; k += 4) {
        f32x4 a = *(const f32x4*)&qs[k];
        f32x4 b = *(const f32x4*)&w[k];
        acc += a.x * b.x + a.y * b.y + a.z * b.z + a.w * b.w;
      }
      q_out[blk * DIM + o] = acc + bq[o];
    }
  } else {
    const int c = blk - 64;
    const int flat = c * 4096 + tid * 16;
    const int o = flat >> 9, k0 = flat & 511;
    const int t = k0 >> 5, kk = k0 & 31;
    u16* dst = Wrbt + t * 16384 + o * 32 + kk;
#pragma unroll
    for (int i = 0; i < 4; ++i) {
      f32x4 a = *(const f32x4*)&Wr[flat + i * 4];
      s16x4 o4;
      o4.x = (short)f2bf(a.x); o4.y = (short)f2bf(a.y);
      o4.z = (short)f2bf(a.z); o4.w = (short)f2bf(a.w);
      *(s16x4*)&dst[i * 4] = o4;
    }
  }
}

// ---------- fused: ref-slab transpose + GEMM + full-line e-store epilogue ----------
// grid (64 b fastest, 64 lc). Block = 512o x 32l: 8 waves, each 64o x 32l
// (acc[4][2]). 4 blocks/CU (launch_bounds 512,8). Epilogue repacks acc through
// the dead Bs LDS so every e-store instruction covers 8 FULL 128-B lines
// (kills the two-half-line write-allocate pattern of rounds 1-9).
__global__ __launch_bounds__(512, 8) void gemm_fused(
    const float* __restrict__ ref, const u16* __restrict__ Wrbt,
    const float* __restrict__ q, const float* __restrict__ br,
    const float* __restrict__ v, float* __restrict__ e_out,
    float* __restrict__ logits) {
  __shared__ u16 Bs[32 * 520];    // 33,280 B; reused as 32 KB f32 scratch in epilogue
  __shared__ float u_lds[8][32];

  const int b = blockIdx.x, lc = blockIdx.y;
  const int l0 = lc * 32;
  const int tid = threadIdx.x, lane = tid & 63, w = tid >> 6;
  const int rr = lane & 15, kg = lane >> 4;

  // ---- stage: issue all 8 HBM loads first, then cvt + swizzled ds_write ----
  f32x4 sreg[8];
#pragma unroll
  for (int p = 0; p < 8; ++p) {
    const int row = p * 4 + (tid >> 7);
    const int col4 = tid & 127;
    sreg[p] = __builtin_nontemporal_load(
        (const f32x4*)&ref[((size_t)(l0 + row) * 64 + b) * 512 + col4 * 4]);
  }
#pragma unroll
  for (int p = 0; p < 8; ++p) {
    const int row = p * 4 + (tid >> 7);
    const int col4 = tid & 127;
    s16x4 o4;
    o4.x = (short)f2bf(sreg[p].x); o4.y = (short)f2bf(sreg[p].y);
    o4.z = (short)f2bf(sreg[p].z); o4.w = (short)f2bf(sreg[p].w);
    const int unit = row * 65 + ((col4 >> 1) ^ ((row & 7) << 2));
    *(s16x4*)&Bs[(unit << 3) + ((col4 & 1) << 2)] = o4;
  }
  __syncthreads();

  const u16* ap = Wrbt + (w * 64 + rr) * 32 + kg * 8;

  f32x4 acc[4][2];
#pragma unroll
  for (int fm = 0; fm < 4; ++fm)
#pragma unroll
    for (int fn = 0; fn < 2; ++fn) acc[fm][fn] = (f32x4){0.f, 0.f, 0.f, 0.f};

  s16x8 A0[4], A1[4];
#pragma unroll
  for (int fm = 0; fm < 4; ++fm) {
    A0[fm] = *(const s16x8*)(ap + 0 * 16384 + fm * 512);
    A1[fm] = *(const s16x8*)(ap + 1 * 16384 + fm * 512);
  }

#pragma unroll
  for (int t = 0; t < 16; ++t) {
    s16x8 bf[2];
#pragma unroll
    for (int fn = 0; fn < 2; ++fn) {
      const int row = fn * 16 + rr;
      const int unit = row * 65 + ((t * 4 + kg) ^ ((row & 7) << 2));
      bf[fn] = *(const s16x8*)&Bs[unit << 3];
    }
    if (t & 1) {
#pragma unroll
      for (int fm = 0; fm < 4; ++fm)
#pragma unroll
        for (int fn = 0; fn < 2; ++fn)
          acc[fm][fn] = __builtin_amdgcn_mfma_f32_16x16x32_bf16(bf[fn], A1[fm], acc[fm][fn], 0, 0, 0);
      if (t + 2 < 16)
#pragma unroll
        for (int fm = 0; fm < 4; ++fm)
          A1[fm] = *(const s16x8*)(ap + (t + 2) * 16384 + fm * 512);
    } else {
#pragma unroll
      for (int fm = 0; fm < 4; ++fm)
#pragma unroll
        for (int fn = 0; fn < 2; ++fn)
          acc[fm][fn] = __builtin_amdgcn_mfma_f32_16x16x32_bf16(bf[fn], A0[fm], acc[fm][fn], 0, 0, 0);
      if (t + 2 < 16)
#pragma unroll
        for (int fm = 0; fm < 4; ++fm)
          A0[fm] = *(const s16x8*)(ap + (t + 2) * 16384 + fm * 512);
    }
  }

  // ---- tanh/logits partials (pure register) ----
  float bb[4];
  f32x4 usA[2];
#pragma unroll
  for (int fn = 0; fn < 2; ++fn) usA[fn] = (f32x4){0.f, 0.f, 0.f, 0.f};
#pragma unroll
  for (int fm = 0; fm < 4; ++fm) {
    const int o = w * 64 + fm * 16 + rr;
    bb[fm] = br[o];
    const float qv = q[b * DIM + o] + bb[fm];
    const float vv = v[o];
#pragma unroll
    for (int fn = 0; fn < 2; ++fn) {
      f32x4 a = acc[fm][fn];
      f32x4 th;
      th.x = tanh_fast(a.x + qv);
      th.y = tanh_fast(a.y + qv);
      th.z = tanh_fast(a.z + qv);
      th.w = tanh_fast(a.w + qv);
      usA[fn] += vv * th;
    }
  }
#pragma unroll
  for (int fn = 0; fn < 2; ++fn) {
    f32x4 us = usA[fn];
#pragma unroll
    for (int msk = 1; msk <= 8; msk <<= 1) {
      us.x += __shfl_xor(us.x, msk);
      us.y += __shfl_xor(us.y, msk);
      us.z += __shfl_xor(us.z, msk);
      us.w += __shfl_xor(us.w, msk);
    }
    if (rr == 0)
      *(f32x4*)&u_lds[w][fn * 16 + kg * 4] = us;
  }

  // ---- e-store via LDS repack: two 32KB phases, full-128B-line stores ----
  float* BsF = (float*)Bs;  // 256 rows x 8 units(16B); unit = row*8 + (c ^ (row&7))
  __syncthreads();          // all Bs K-loop reads done
#pragma unroll
  for (int half = 0; half < 2; ++half) {
#pragma unroll
    for (int fm2 = 0; fm2 < 2; ++fm2) {
      const int fm = half * 2 + fm2;
      const int row = w * 32 + fm2 * 16 + rr;
#pragma unroll
      for (int fn = 0; fn < 2; ++fn) {
        const int c = fn * 4 + kg;
        f32x4 ev = acc[fm][fn] + bb[fm];
        *(f32x4*)&BsF[(row * 8 + (c ^ (row & 7))) * 4] = ev;
      }
    }
    __syncthreads();
#pragma unroll
    for (int p = 0; p < 4; ++p) {
      const int idx = p * 512 + tid;
      const int row = idx >> 3, cu = idx & 7;
      const int o = ((row >> 5) << 6) + half * 32 + (row & 31);
      f32x4 ev = *(const f32x4*)&BsF[(row * 8 + (cu ^ (row & 7))) * 4];
      __builtin_nontemporal_store(
          ev, (f32x4*)&e_out[((size_t)(b * DIM + o)) * L_ + l0 + cu * 4]);
    }
    __syncthreads();
  }

  if (tid < 32) {
    float s = 0.f;
#pragma unroll
    for (int ww = 0; ww < 8; ++ww) s += u_lds[ww][tid];
    logits[(size_t)b * L_ + l0 + tid] = s;
  }
}

extern "C" void kernel_launch(void* const* d_in, const int* in_sizes, int n_in,
                              void* d_out, int out_size, void* d_ws, size_t ws_size,
                              hipStream_t stream) {
  const float* query = (const float*)d_in[0];
  const float* ref   = (const float*)d_in[1];
  const float* Wq    = (const float*)d_in[2];
  const float* bq    = (const float*)d_in[3];
  const float* Wr    = (const float*)d_in[4];
  const float* br    = (const float*)d_in[5];
  const float* v     = (const float*)d_in[6];

  float* e_out  = (float*)d_out;
  float* logits = e_out + (size_t)B_ * DIM * L_;  // 67108864

  char* ws = (char*)d_ws;
  u16*   Wrbt = (u16*)ws;               // 512 KB [16][512][32]
  float* q    = (float*)(ws + 524288);  // 128 KB

  prep_kernel<<<128, 256, 0, stream>>>(query, Wq, bq, Wr, q, Wrbt);
  gemm_fused<<<dim3(64, 64), 512, 0, stream>>>(ref, Wrbt, q, br, v, e_out, logits);
}

// Round 11
// 241.368 us; speedup vs baseline: 1.0531x; 1.0531x over previous
//
#include <hip/hip_runtime.h>

#define DIM 512
#define B_  64
#define L_  2048

typedef unsigned short u16;
typedef float f32x4 __attribute__((ext_vector_type(4)));
typedef short s16x8 __attribute__((ext_vector_type(8)));
typedef short s16x4 __attribute__((ext_vector_type(4)));

__device__ __forceinline__ u16 f2bf(float f) {
  union { float f; unsigned u; } x{f};
  unsigned r = x.u + 0x7FFFu + ((x.u >> 16) & 1u);
  return (u16)(r >> 16);
}

__device__ __forceinline__ float tanh_fast(float x) {
  float e2 = __expf(2.0f * x);
  return 1.0f - 2.0f / (e2 + 1.0f);
}

// ---------- prep: q = query @ Wq^T + bq ; Wr -> bf16 transposed [t][o][32k] ----------
__global__ __launch_bounds__(256) void prep_kernel(
    const float* __restrict__ query, const float* __restrict__ Wq,
    const float* __restrict__ bq, const float* __restrict__ Wr,
    float* __restrict__ q_out, u16* __restrict__ Wrbt) {
  const int blk = blockIdx.x;
  const int tid = threadIdx.x;
  if (blk < 64) {
    __shared__ float qs[DIM];
    for (int i = tid; i < DIM; i += 256) qs[i] = query[blk * DIM + i];
    __syncthreads();
    for (int o = tid; o < DIM; o += 256) {
      const float* w = Wq + o * DIM;
      float acc = 0.f;
      for (int k = 0; k < DIM; k += 4) {
        f32x4 a = *(const f32x4*)&qs[k];
        f32x4 b = *(const f32x4*)&w[k];
        acc += a.x * b.x + a.y * b.y + a.z * b.z + a.w * b.w;
      }
      q_out[blk * DIM + o] = acc + bq[o];
    }
  } else {
    const int c = blk - 64;
    const int flat = c * 4096 + tid * 16;
    const int o = flat >> 9, k0 = flat & 511;
    const int t = k0 >> 5, kk = k0 & 31;
    u16* dst = Wrbt + t * 16384 + o * 32 + kk;
#pragma unroll
    for (int i = 0; i < 4; ++i) {
      f32x4 a = *(const f32x4*)&Wr[flat + i * 4];
      s16x4 o4;
      o4.x = (short)f2bf(a.x); o4.y = (short)f2bf(a.y);
      o4.z = (short)f2bf(a.z); o4.w = (short)f2bf(a.w);
      *(s16x4*)&dst[i * 4] = o4;
    }
  }
}

// ---------- fused: ref-slab transpose (in-block) + GEMM + epilogue ----------
// grid (64 lc FASTEST, 64 b): co-resident blocks = all 64 l-chunks x 16 b, so
// the 64 pieces of each 8KB e-row are written in a tight temporal window and
// the GPU-wide write front is 16 dense 4MB slabs (DRAM page locality), not
// scattered 128B granules. Kernel body identical to round 9.
__global__ __launch_bounds__(512, 8) void gemm_fused(
    const float* __restrict__ ref, const u16* __restrict__ Wrbt,
    const float* __restrict__ q, const float* __restrict__ br,
    const float* __restrict__ v, float* __restrict__ e_out,
    float* __restrict__ logits) {
  __shared__ u16 Bs[32 * 520];    // 33,280 B (65 units x 16B per row)
  __shared__ float u_lds[8][32];

  const int lc = blockIdx.x, b = blockIdx.y;   // <-- swapped vs round 9
  const int l0 = lc * 32;
  const int tid = threadIdx.x, lane = tid & 63, w = tid >> 6;
  const int rr = lane & 15, kg = lane >> 4;

  // ---- stage: issue all 8 HBM loads first, then cvt + swizzled ds_write ----
  f32x4 sreg[8];
#pragma unroll
  for (int p = 0; p < 8; ++p) {
    const int row = p * 4 + (tid >> 7);
    const int col4 = tid & 127;
    sreg[p] = __builtin_nontemporal_load(
        (const f32x4*)&ref[((size_t)(l0 + row) * 64 + b) * 512 + col4 * 4]);
  }
#pragma unroll
  for (int p = 0; p < 8; ++p) {
    const int row = p * 4 + (tid >> 7);
    const int col4 = tid & 127;
    s16x4 o4;
    o4.x = (short)f2bf(sreg[p].x); o4.y = (short)f2bf(sreg[p].y);
    o4.z = (short)f2bf(sreg[p].z); o4.w = (short)f2bf(sreg[p].w);
    const int unit = row * 65 + ((col4 >> 1) ^ ((row & 7) << 2));
    *(s16x4*)&Bs[(unit << 3) + ((col4 & 1) << 2)] = o4;
  }
  __syncthreads();

  const u16* ap = Wrbt + (w * 64 + rr) * 32 + kg * 8;

  f32x4 acc[4][2];
#pragma unroll
  for (int fm = 0; fm < 4; ++fm)
#pragma unroll
    for (int fn = 0; fn < 2; ++fn) acc[fm][fn] = (f32x4){0.f, 0.f, 0.f, 0.f};

  // depth-2 static A double-buffer
  s16x8 A0[4], A1[4];
#pragma unroll
  for (int fm = 0; fm < 4; ++fm) {
    A0[fm] = *(const s16x8*)(ap + 0 * 16384 + fm * 512);
    A1[fm] = *(const s16x8*)(ap + 1 * 16384 + fm * 512);
  }

#pragma unroll
  for (int t = 0; t < 16; ++t) {
    s16x8 bf[2];
#pragma unroll
    for (int fn = 0; fn < 2; ++fn) {
      const int row = fn * 16 + rr;
      const int unit = row * 65 + ((t * 4 + kg) ^ ((row & 7) << 2));
      bf[fn] = *(const s16x8*)&Bs[unit << 3];
    }
    if (t & 1) {
#pragma unroll
      for (int fm = 0; fm < 4; ++fm)
#pragma unroll
        for (int fn = 0; fn < 2; ++fn)
          acc[fm][fn] = __builtin_amdgcn_mfma_f32_16x16x32_bf16(bf[fn], A1[fm], acc[fm][fn], 0, 0, 0);
      if (t + 2 < 16)
#pragma unroll
        for (int fm = 0; fm < 4; ++fm)
          A1[fm] = *(const s16x8*)(ap + (t + 2) * 16384 + fm * 512);
    } else {
#pragma unroll
      for (int fm = 0; fm < 4; ++fm)
#pragma unroll
        for (int fn = 0; fn < 2; ++fn)
          acc[fm][fn] = __builtin_amdgcn_mfma_f32_16x16x32_bf16(bf[fn], A0[fm], acc[fm][fn], 0, 0, 0);
      if (t + 2 < 16)
#pragma unroll
        for (int fm = 0; fm < 4; ++fm)
          A0[fm] = *(const s16x8*)(ap + (t + 2) * 16384 + fm * 512);
    }
  }

  // ---- epilogue: e = acc + br ; u = sum_o v * tanh(acc + q + br) ----
  f32x4 usA[2];
#pragma unroll
  for (int fn = 0; fn < 2; ++fn) usA[fn] = (f32x4){0.f, 0.f, 0.f, 0.f};
#pragma unroll
  for (int fm = 0; fm < 4; ++fm) {
    const int o = w * 64 + fm * 16 + rr;
    const float brv = br[o];
    const float qv = q[b * DIM + o] + brv;
    const float vv = v[o];
    const size_t erow = ((size_t)(b * DIM + o)) * L_;
#pragma unroll
    for (int fn = 0; fn < 2; ++fn) {
      const int lb = l0 + fn * 16 + kg * 4;
      f32x4 a = acc[fm][fn];
      f32x4 ev = a + brv;
      *(f32x4*)&e_out[erow + lb] = ev;
      f32x4 th;
      th.x = tanh_fast(a.x + qv);
      th.y = tanh_fast(a.y + qv);
      th.z = tanh_fast(a.z + qv);
      th.w = tanh_fast(a.w + qv);
      usA[fn] += vv * th;
    }
  }
#pragma unroll
  for (int fn = 0; fn < 2; ++fn) {
    f32x4 us = usA[fn];
#pragma unroll
    for (int msk = 1; msk <= 8; msk <<= 1) {  // reduce over rr (o dim)
      us.x += __shfl_xor(us.x, msk);
      us.y += __shfl_xor(us.y, msk);
      us.z += __shfl_xor(us.z, msk);
      us.w += __shfl_xor(us.w, msk);
    }
    if (rr == 0)
      *(f32x4*)&u_lds[w][fn * 16 + kg * 4] = us;
  }
  __syncthreads();
  if (tid < 32) {
    float s = 0.f;
#pragma unroll
    for (int ww = 0; ww < 8; ++ww) s += u_lds[ww][tid];
    logits[(size_t)b * L_ + l0 + tid] = s;
  }
}

extern "C" void kernel_launch(void* const* d_in, const int* in_sizes, int n_in,
                              void* d_out, int out_size, void* d_ws, size_t ws_size,
                              hipStream_t stream) {
  const float* query = (const float*)d_in[0];
  const float* ref   = (const float*)d_in[1];
  const float* Wq    = (const float*)d_in[2];
  const float* bq    = (const float*)d_in[3];
  const float* Wr    = (const float*)d_in[4];
  const float* br    = (const float*)d_in[5];
  const float* v     = (const float*)d_in[6];

  float* e_out  = (float*)d_out;
  float* logits = e_out + (size_t)B_ * DIM * L_;  // 67108864

  char* ws = (char*)d_ws;
  u16*   Wrbt = (u16*)ws;               // 512 KB [16][512][32]
  float* q    = (float*)(ws + 524288);  // 128 KB

  prep_kernel<<<128, 256, 0, stream>>>(query, Wq, bq, Wr, q, Wrbt);
  gemm_fused<<<dim3(64, 64), 512, 0, stream>>>(ref, Wrbt, q, br, v, e_out, logits);
}